// Round 6
// baseline (590.624 us; speedup 1.0000x reference)
//
#include <hip/hip_runtime.h>

#define FDIM 128

typedef __attribute__((ext_vector_type(8))) short bf16x8;
typedef __attribute__((ext_vector_type(4))) float f32x4;

// Column permutation for internal Z/S storage (within a 128-col half):
//   orig c: ct=c>>4, n=c&15  ->  stored s = 64*(ct>=4) + n*4 + (ct&3)
//   inv:    hi=s>>6, s6=s&63, n=s6>>2, ctl=s6&3 -> c = (ctl+4*hi)*16 + n
// Each lane's 4 ctl accumulators are contiguous in storage (8B packed stores
// in the GEMM epilogue, 16B gathers in aggregation).

__device__ __forceinline__ unsigned short f2bf(float f){
  unsigned int u = __float_as_uint(f);
  unsigned int r = u + 0x7FFFu + ((u >> 16) & 1u);
  return (unsigned short)(r >> 16);
}

// ---------------- init: zero cnt, zero dummy Z/Z2 rows, build Wcat ----------------
// Wcat[layer][256][128] bf16; rows 0..127 = Wl, 128..255 = Wr.
// Layer-2 weights get inverse-permuted k (their A input h is in permuted space).
__global__ void k_init(const float* __restrict__ Wl0, const float* __restrict__ Wr0,
                       const float* __restrict__ Wl1, const float* __restrict__ Wr1,
                       unsigned short* __restrict__ Wcat, int* __restrict__ cnt,
                       unsigned short* __restrict__ Zdummy, unsigned short* __restrict__ Z2dummy,
                       int N, int nb){
  int b = blockIdx.x;
  if (b < nb){
    int i = b*256 + threadIdx.x;
    if (i < N) cnt[i] = 0;
    if (b == 0 && threadIdx.x < FDIM){
      Zdummy[threadIdx.x]  = 0;
      Z2dummy[threadIdx.x] = 0;
    }
  } else {
    int i = (b - nb)*256 + threadIdx.x;     // 0 .. 65535
    int l   = i >> 15;
    int rem = i & 32767;
    int row = rem >> 7, k = rem & 127;
    int ksrc = k;
    if (l == 1){
      int hi = k >> 6, s6 = k & 63;
      ksrc = ((s6 & 3) + 4*hi)*16 + (s6 >> 2);   // invPerm(k)
    }
    const float* W = (l == 0) ? ((row < 128) ? Wl0 : Wr0)
                              : ((row < 128) ? Wl1 : Wr1);
    Wcat[i] = f2bf(W[(row & 127)*128 + ksrc]);
  }
}

// ---------------- degree ----------------
__global__ void k_degree(const int* __restrict__ dst, int* __restrict__ cnt, int E){
  int e = blockIdx.x*256 + threadIdx.x;
  if (e < E) atomicAdd(&cnt[dst[e]], 1);
}

// ---------------- scan: padded-degree exclusive scan + padding dummies ----------------
// Single workgroup of 1024 threads, blocked assignment + LDS block-scan.
// Writes row_off/cursor and fills padding slots [ro+deg, ro+pdeg) with N.
__global__ __launch_bounds__(1024)
void k_scan(const int* __restrict__ cnt, int* __restrict__ row_off,
            int* __restrict__ cursor, int* __restrict__ csr_src, int N){
  __shared__ int s[1024];
  int tid = threadIdx.x;
  int chunk = (N + 1023)/1024;
  int i0 = tid*chunk; if (i0 > N) i0 = N;
  int i1 = i0 + chunk; if (i1 > N) i1 = N;
  int sum = 0;
  for (int i = i0; i < i1; i++) sum += (cnt[i] + 7) & ~7;
  s[tid] = sum; __syncthreads();
  for (int off = 1; off < 1024; off <<= 1){
    int t = (tid >= off) ? s[tid - off] : 0;
    __syncthreads();
    s[tid] += t;
    __syncthreads();
  }
  int off = s[tid] - sum;              // exclusive
  for (int i = i0; i < i1; i++){
    int d  = cnt[i];
    int pd = (d + 7) & ~7;
    row_off[i] = off;
    cursor[i]  = off;
    for (int p = d; p < pd; p++) csr_src[off + p] = N;   // dummy -> zero row
    off += pd;
  }
}

// ---------------- fill ----------------
__global__ void k_fill(const int* __restrict__ src, const int* __restrict__ dst,
                       int* __restrict__ cursor, int* __restrict__ csr_src, int E){
  int e = blockIdx.x*256 + threadIdx.x;
  if (e >= E) return;
  int d = dst[e];
  int pos = atomicAdd(&cursor[d], 1);
  csr_src[pos] = src[e];
}

// ---------------- layer-1 dual GEMM: Z = X@Wl^T, S = X@Wr^T + (bl+br) ----------------
// fp32 A input, permuted-col bf16 output. Register-prefetch pipelined (R5).
__global__ __launch_bounds__(256, 2)
void k_dualgemm1(const float* __restrict__ X, const unsigned short* __restrict__ Wcat,
                 const float* __restrict__ bl, const float* __restrict__ br,
                 unsigned short* __restrict__ Z, unsigned short* __restrict__ S,
                 int N, int nrb){
  __shared__ unsigned short lds[64*FDIM];
  const int tid  = threadIdx.x;
  const int wave = tid >> 6;
  const int lane = tid & 63;
  const int n = lane & 15, q = lane >> 4;

  float bias[4];
#pragma unroll
  for (int ctl = 0; ctl < 4; ctl++){
    int ct = wave*4 + ctl;
    if (ct >= 8){ int col = (ct - 8)*16 + n; bias[ctl] = bl[col] + br[col]; }
    else bias[ctl] = 0.0f;
  }

  float4 pf[8];
  const int r_   = tid >> 4;
  const int c16_ = tid & 15;

  auto issue_load = [&](int rb){
    int row0 = rb*64;
#pragma unroll
    for (int it = 0; it < 4; it++){
      int r  = r_ + it*16;
      int gr = row0 + r;
      if (gr < N){
        const float4* sp = (const float4*)(X + (size_t)gr*FDIM + c16_*8);
        pf[2*it]   = sp[0];
        pf[2*it+1] = sp[1];
      } else {
        pf[2*it]   = make_float4(0,0,0,0);
        pf[2*it+1] = make_float4(0,0,0,0);
      }
    }
  };

  int rb = blockIdx.x;
  if (rb < nrb) issue_load(rb);

  for (; rb < nrb; rb += gridDim.x){
    int row0 = rb*64;
    __syncthreads();
#pragma unroll
    for (int it = 0; it < 4; it++){
      int r = r_ + it*16;
      float4 v0 = pf[2*it], v1 = pf[2*it+1];
      bf16x8 p;
      p[0] = (short)f2bf(v0.x); p[1] = (short)f2bf(v0.y);
      p[2] = (short)f2bf(v0.z); p[3] = (short)f2bf(v0.w);
      p[4] = (short)f2bf(v1.x); p[5] = (short)f2bf(v1.y);
      p[6] = (short)f2bf(v1.z); p[7] = (short)f2bf(v1.w);
      *(bf16x8*)(lds + r*FDIM + ((c16_ ^ (r & 15)) * 8)) = p;
    }
    __syncthreads();

    int rbn = rb + gridDim.x;
    if (rbn < nrb) issue_load(rbn);

    f32x4 acc[4][4];
#pragma unroll
    for (int rt = 0; rt < 4; rt++)
#pragma unroll
      for (int ctl = 0; ctl < 4; ctl++)
        acc[rt][ctl] = (f32x4){0.f, 0.f, 0.f, 0.f};

#pragma unroll
    for (int kk = 0; kk < 4; kk++){
      bf16x8 bfr[4];
#pragma unroll
      for (int ctl = 0; ctl < 4; ctl++){
        int row = (wave*4 + ctl)*16 + n;
        bfr[ctl] = *(const bf16x8*)(Wcat + row*FDIM + kk*32 + q*8);
      }
      bf16x8 afr[4];
#pragma unroll
      for (int rt = 0; rt < 4; rt++){
        int r = rt*16 + n;
        int c16 = (kk*4 + q) ^ n;
        afr[rt] = *(const bf16x8*)(lds + r*FDIM + c16*8);
      }
#pragma unroll
      for (int rt = 0; rt < 4; rt++)
#pragma unroll
        for (int ctl = 0; ctl < 4; ctl++)
          acc[rt][ctl] = __builtin_amdgcn_mfma_f32_16x16x32_bf16(
              afr[rt], bfr[ctl], acc[rt][ctl], 0, 0, 0);
    }

    unsigned short* dstb = (wave < 2) ? Z : S;
    int s0 = 64*(wave & 1) + n*4;
#pragma unroll
    for (int rt = 0; rt < 4; rt++){
#pragma unroll
      for (int r = 0; r < 4; r++){
        int grow = row0 + rt*16 + q*4 + r;
        if (grow < N){
          float v0 = acc[rt][0][r] + bias[0];
          float v1 = acc[rt][1][r] + bias[1];
          float v2 = acc[rt][2][r] + bias[2];
          float v3 = acc[rt][3][r] + bias[3];
          uint2 u;
          u.x = ((unsigned)f2bf(v1) << 16) | (unsigned)f2bf(v0);
          u.y = ((unsigned)f2bf(v3) << 16) | (unsigned)f2bf(v2);
          *(uint2*)(dstb + (size_t)grow*FDIM + s0) = u;
        }
      }
    }
  }
}

// ---------------- fused layer-1 aggregate + layer-2 dual GEMM ----------------
// Staging computes h = relu(mean(Z[src]) + S) on the fly (permuted space) into
// LDS, then MFMA with layer-2 weights. Z2 separate from Z (cross-block gather
// reads); S reused in place (row-disjoint across blocks, read-before-write).
__global__ __launch_bounds__(256, 2)
void k_agg_gemm(const unsigned short* __restrict__ Z, unsigned short* __restrict__ S,
                const int* __restrict__ row_off, const int* __restrict__ cnt,
                const int* __restrict__ csr_src,
                const unsigned short* __restrict__ Wcat,
                const float* __restrict__ bl, const float* __restrict__ br,
                unsigned short* __restrict__ Z2, int N, int nrb){
  __shared__ unsigned short lds[64*FDIM];
  const int tid  = threadIdx.x;
  const int wave = tid >> 6;
  const int lane = tid & 63;
  const int n = lane & 15, q = lane >> 4;
  const int g16   = lane & 15;   // pos within 16-lane row-group == 16B chunk idx
  const int gbase = lane & 48;   // first lane of this row-group

  float bias[4];
#pragma unroll
  for (int ctl = 0; ctl < 4; ctl++){
    int ct = wave*4 + ctl;
    if (ct >= 8){ int col = (ct - 8)*16 + n; bias[ctl] = bl[col] + br[col]; }
    else bias[ctl] = 0.0f;
  }

  for (int rb = blockIdx.x; rb < nrb; rb += gridDim.x){
    int row0 = rb*64;
    __syncthreads();
    // ---- staging: build h rows (layer-1 aggregate, permuted space) ----
#pragma unroll
    for (int it = 0; it < 4; it++){
      int r  = (tid >> 4) + it*16;
      int gr = row0 + r;
      bf16x8 p;
      if (gr < N){
        int ro  = row_off[gr];
        int deg = cnt[gr];
        float inv = 1.0f / (float)(deg > 1 ? deg : 1);
        float hacc[8];
#pragma unroll
        for (int z = 0; z < 8; z++) hacc[z] = 0.f;
        for (int base = 0; base < deg; base += 16){
          int m = deg - base; if (m > 16) m = 16;
          int sidx = (g16 < m) ? csr_src[ro + base + g16] : 0;
          for (int j = 0; j < m; j += 8){
            int id[8];
#pragma unroll
            for (int t = 0; t < 8; t++){
              int sl = j + t; if (sl >= m) sl = 0;      // group-uniform clamp
              id[t] = __shfl(sidx, gbase + sl);
            }
            uint4 v[8];
#pragma unroll
            for (int t = 0; t < 8; t++){
              unsigned u = (unsigned)id[t];
              if (u > (unsigned)N) u = (unsigned)N;     // defensive (row N = zeros)
              v[t] = *(const uint4*)(Z + (size_t)u*FDIM + g16*8);  // 8 gathers in flight
            }
#pragma unroll
            for (int t = 0; t < 8; t++){
              if (j + t < m){
                hacc[0] += __uint_as_float(v[t].x << 16);
                hacc[1] += __uint_as_float(v[t].x & 0xFFFF0000u);
                hacc[2] += __uint_as_float(v[t].y << 16);
                hacc[3] += __uint_as_float(v[t].y & 0xFFFF0000u);
                hacc[4] += __uint_as_float(v[t].z << 16);
                hacc[5] += __uint_as_float(v[t].z & 0xFFFF0000u);
                hacc[6] += __uint_as_float(v[t].w << 16);
                hacc[7] += __uint_as_float(v[t].w & 0xFFFF0000u);
              }
            }
          }
        }
        uint4 sv = *(const uint4*)(S + (size_t)gr*FDIM + g16*8);
        float s0 = __uint_as_float(sv.x << 16), s1 = __uint_as_float(sv.x & 0xFFFF0000u);
        float s2 = __uint_as_float(sv.y << 16), s3 = __uint_as_float(sv.y & 0xFFFF0000u);
        float s4 = __uint_as_float(sv.z << 16), s5 = __uint_as_float(sv.z & 0xFFFF0000u);
        float s6 = __uint_as_float(sv.w << 16), s7 = __uint_as_float(sv.w & 0xFFFF0000u);
        p[0] = (short)f2bf(fmaxf(hacc[0]*inv + s0, 0.f));
        p[1] = (short)f2bf(fmaxf(hacc[1]*inv + s1, 0.f));
        p[2] = (short)f2bf(fmaxf(hacc[2]*inv + s2, 0.f));
        p[3] = (short)f2bf(fmaxf(hacc[3]*inv + s3, 0.f));
        p[4] = (short)f2bf(fmaxf(hacc[4]*inv + s4, 0.f));
        p[5] = (short)f2bf(fmaxf(hacc[5]*inv + s5, 0.f));
        p[6] = (short)f2bf(fmaxf(hacc[6]*inv + s6, 0.f));
        p[7] = (short)f2bf(fmaxf(hacc[7]*inv + s7, 0.f));
      } else {
#pragma unroll
        for (int z = 0; z < 8; z++) p[z] = 0;
      }
      *(bf16x8*)(lds + r*FDIM + ((g16 ^ (r & 15)) * 8)) = p;
    }
    __syncthreads();

    // ---- MFMA with layer-2 weights ----
    f32x4 acc[4][4];
#pragma unroll
    for (int rt = 0; rt < 4; rt++)
#pragma unroll
      for (int ctl = 0; ctl < 4; ctl++)
        acc[rt][ctl] = (f32x4){0.f, 0.f, 0.f, 0.f};

#pragma unroll
    for (int kk = 0; kk < 4; kk++){
      bf16x8 bfr[4];
#pragma unroll
      for (int ctl = 0; ctl < 4; ctl++){
        int row = (wave*4 + ctl)*16 + n;
        bfr[ctl] = *(const bf16x8*)(Wcat + row*FDIM + kk*32 + q*8);
      }
      bf16x8 afr[4];
#pragma unroll
      for (int rt = 0; rt < 4; rt++){
        int r = rt*16 + n;
        int c16 = (kk*4 + q) ^ n;
        afr[rt] = *(const bf16x8*)(lds + r*FDIM + c16*8);
      }
#pragma unroll
      for (int rt = 0; rt < 4; rt++)
#pragma unroll
        for (int ctl = 0; ctl < 4; ctl++)
          acc[rt][ctl] = __builtin_amdgcn_mfma_f32_16x16x32_bf16(
              afr[rt], bfr[ctl], acc[rt][ctl], 0, 0, 0);
    }

    // ---- epilogue: Z2 / S (in place) ----
    unsigned short* dstb = (wave < 2) ? Z2 : S;
    int s0c = 64*(wave & 1) + n*4;
#pragma unroll
    for (int rt = 0; rt < 4; rt++){
#pragma unroll
      for (int r = 0; r < 4; r++){
        int grow = row0 + rt*16 + q*4 + r;
        if (grow < N){
          float v0 = acc[rt][0][r] + bias[0];
          float v1 = acc[rt][1][r] + bias[1];
          float v2 = acc[rt][2][r] + bias[2];
          float v3 = acc[rt][3][r] + bias[3];
          uint2 u;
          u.x = ((unsigned)f2bf(v1) << 16) | (unsigned)f2bf(v0);
          u.y = ((unsigned)f2bf(v3) << 16) | (unsigned)f2bf(v2);
          *(uint2*)(dstb + (size_t)grow*FDIM + s0c) = u;
        }
      }
    }
  }
}

// ---------------- final aggregate: out = relu(sum(Z2[src])/deg + S) ----------------
// One wave per node, padded CSR, dwordx2 gathers, xor-32 combine, un-permuted store.
__global__ __launch_bounds__(256)
void k_aggregate(const unsigned short* __restrict__ Z2, const unsigned short* __restrict__ S,
                 const int* __restrict__ row_off, const int* __restrict__ cnt,
                 const int* __restrict__ csr_src, float* __restrict__ Out, int N){
  int wave = threadIdx.x >> 6, lane = threadIdx.x & 63;
  int node = blockIdx.x*4 + wave;
  if (node >= N) return;
  int start = row_off[node];
  int deg   = cnt[node];
  int pdeg  = (deg + 7) & ~7;
  float inv = 1.0f / (float)(deg > 1 ? deg : 1);
  int L = lane & 31, half = lane >> 5;
  uint2 sv = *(const uint2*)(S + (size_t)node*FDIM + L*4);

  const int* cb = csr_src + start;
  float a0 = 0.f, a1 = 0.f, a2 = 0.f, a3 = 0.f;
  for (int base = 0; base < pdeg; base += 64){
    int m = pdeg - base; if (m > 64) m = 64;      // multiple of 8
    int sidx = (lane < m) ? cb[base + lane] : N;
    for (int j = 0; j < m; j += 8){
      int id[4];
#pragma unroll
      for (int t = 0; t < 4; t++)
        id[t] = __shfl(sidx, j + 2*t + half);
      uint2 v[4];
#pragma unroll
      for (int t = 0; t < 4; t++){
        unsigned u = (unsigned)id[t];
        if (u > (unsigned)N) u = (unsigned)N;     // dummy/defensive -> zero row
        v[t] = *(const uint2*)(Z2 + (size_t)u*FDIM + L*4);
      }
#pragma unroll
      for (int t = 0; t < 4; t++){
        a0 += __uint_as_float(v[t].x << 16);
        a1 += __uint_as_float(v[t].x & 0xFFFF0000u);
        a2 += __uint_as_float(v[t].y << 16);
        a3 += __uint_as_float(v[t].y & 0xFFFF0000u);
      }
    }
  }
  a0 += __shfl_xor(a0, 32);
  a1 += __shfl_xor(a1, 32);
  a2 += __shfl_xor(a2, 32);
  a3 += __shfl_xor(a3, 32);
  float o0 = fmaxf(a0*inv + __uint_as_float(sv.x << 16),          0.f);
  float o1 = fmaxf(a1*inv + __uint_as_float(sv.x & 0xFFFF0000u),  0.f);
  float o2 = fmaxf(a2*inv + __uint_as_float(sv.y << 16),          0.f);
  float o3 = fmaxf(a3*inv + __uint_as_float(sv.y & 0xFFFF0000u),  0.f);
  // un-permute: stored s = L*4+e -> orig c = (e+4*hi)*16 + nn
  int nn = L & 15, hi = L >> 4;
  float e0v = half ? o2 : o0;
  float e1v = half ? o3 : o1;
  int e0 = 2*half, e1 = 2*half + 1;
  Out[(size_t)node*FDIM + (e0 + 4*hi)*16 + nn] = e0v;
  Out[(size_t)node*FDIM + (e1 + 4*hi)*16 + nn] = e1v;
}

extern "C" void kernel_launch(void* const* d_in, const int* in_sizes, int n_in,
                              void* d_out, int out_size, void* d_ws, size_t ws_size,
                              hipStream_t stream){
  const float* x   = (const float*)d_in[0];
  const int*   eix = (const int*)d_in[1];
  const float* Wl0 = (const float*)d_in[2];
  const float* bl0 = (const float*)d_in[3];
  const float* Wr0 = (const float*)d_in[4];
  const float* br0 = (const float*)d_in[5];
  const float* Wl1 = (const float*)d_in[6];
  const float* bl1 = (const float*)d_in[7];
  const float* Wr1 = (const float*)d_in[8];
  const float* br1 = (const float*)d_in[9];
  float* out = (float*)d_out;

  int N = in_sizes[0] / FDIM;
  int E = in_sizes[1] / 2;
  const int* src = eix;
  const int* dst = eix + E;

  // workspace (Z and Z2 have N+1 rows: row N is the zero dummy row)
  unsigned short* Z    = (unsigned short*)d_ws;
  unsigned short* Z2   = Z  + (size_t)(N + 1)*FDIM;
  unsigned short* S    = Z2 + (size_t)(N + 1)*FDIM;
  unsigned short* Wcat = S  + (size_t)N*FDIM;
  int* cnt     = (int*)(Wcat + 2*256*128);
  int* row_off = cnt + N;
  int* cursor  = row_off + N;
  int* csr_src = cursor + N;                 // capacity: E + 7N (padding bound)

  int nb = (N + 255)/256;

  k_init   <<<nb + 256, 256, 0, stream>>>(Wl0, Wr0, Wl1, Wr1, Wcat, cnt,
                                          Z + (size_t)N*FDIM, Z2 + (size_t)N*FDIM, N, nb);
  k_degree <<<(E + 255)/256, 256, 0, stream>>>(dst, cnt, E);
  k_scan   <<<1, 1024, 0, stream>>>(cnt, row_off, cursor, csr_src, N);
  k_fill   <<<(E + 255)/256, 256, 0, stream>>>(src, dst, cursor, csr_src, E);

  int nrb = (N + 63)/64;
  k_dualgemm1<<<512, 256, 0, stream>>>(x, Wcat, bl0, br0, Z, S, N, nrb);
  k_agg_gemm <<<512, 256, 0, stream>>>(Z, S, row_off, cnt, csr_src,
                                       Wcat + 256*128, bl1, br1, Z2, N, nrb);
  k_aggregate<<<(N + 3)/4, 256, 0, stream>>>(Z2, S, row_off, cnt, csr_src, out, N);
}

// Round 7
// 286.930 us; speedup vs baseline: 2.0584x; 2.0584x over previous
//
#include <hip/hip_runtime.h>

#define FDIM 128

typedef __attribute__((ext_vector_type(8))) short bf16x8;
typedef __attribute__((ext_vector_type(4))) float f32x4;

// Column permutation for internal Z/S storage (within a 128-col half):
//   orig c: ct=c>>4, n=c&15  ->  stored s = 64*(ct>=4) + n*4 + (ct&3)
//   inv:    hi=s>>6, s6=s&63, n=s6>>2, ctl=s6&3 -> c = (ctl+4*hi)*16 + n

__device__ __forceinline__ unsigned short f2bf(float f){
  unsigned int u = __float_as_uint(f);
  unsigned int r = u + 0x7FFFu + ((u >> 16) & 1u);
  return (unsigned short)(r >> 16);
}

// ---------------- init: zero cnt, zero dummy Z/Z2 rows, build Wcat ----------------
__global__ void k_init(const float* __restrict__ Wl0, const float* __restrict__ Wr0,
                       const float* __restrict__ Wl1, const float* __restrict__ Wr1,
                       unsigned short* __restrict__ Wcat, int* __restrict__ cnt,
                       unsigned short* __restrict__ Zdummy, unsigned short* __restrict__ Z2dummy,
                       int N, int nb){
  int b = blockIdx.x;
  if (b < nb){
    int i = b*256 + threadIdx.x;
    if (i < N) cnt[i] = 0;
    if (b == 0 && threadIdx.x < FDIM){
      Zdummy[threadIdx.x]  = 0;
      Z2dummy[threadIdx.x] = 0;
    }
  } else {
    int i = (b - nb)*256 + threadIdx.x;     // 0 .. 65535
    int l   = i >> 15;
    int rem = i & 32767;
    int row = rem >> 7, k = rem & 127;
    int ksrc = k;
    if (l == 1){
      int hi = k >> 6, s6 = k & 63;
      ksrc = ((s6 & 3) + 4*hi)*16 + (s6 >> 2);   // invPerm(k)
    }
    const float* W = (l == 0) ? ((row < 128) ? Wl0 : Wr0)
                              : ((row < 128) ? Wl1 : Wr1);
    Wcat[i] = f2bf(W[(row & 127)*128 + ksrc]);
  }
}

// ---------------- degree ----------------
__global__ void k_degree(const int* __restrict__ dst, int* __restrict__ cnt, int E){
  int e = blockIdx.x*256 + threadIdx.x;
  if (e < E) atomicAdd(&cnt[dst[e]], 1);
}

// ---------------- hierarchical scan over PADDED degrees (R5-proven) ----------------
__global__ void k_scan_blocks(const int* __restrict__ cnt, int* __restrict__ excl,
                              int* __restrict__ partials, int N){
  __shared__ int s[256];
  int tid = threadIdx.x;
  int i = blockIdx.x*256 + tid;
  int v = (i < N) ? ((cnt[i] + 7) & ~7) : 0;
  s[tid] = v; __syncthreads();
  for (int off = 1; off < 256; off <<= 1){
    int t = (tid >= off) ? s[tid - off] : 0;
    __syncthreads();
    s[tid] += t;
    __syncthreads();
  }
  if (i < N) excl[i] = s[tid] - v;
  if (tid == 255) partials[blockIdx.x] = s[255];
}

__global__ void k_scan_partials(int* __restrict__ partials, int nb){
  __shared__ int s[512];
  int tid = threadIdx.x;
  int v = (tid < nb) ? partials[tid] : 0;
  s[tid] = v; __syncthreads();
  for (int off = 1; off < 512; off <<= 1){
    int t = (tid >= off) ? s[tid - off] : 0;
    __syncthreads();
    s[tid] += t;
    __syncthreads();
  }
  if (tid < nb) partials[tid] = s[tid] - v;
}

__global__ void k_finalize(int* __restrict__ row_off, const int* __restrict__ partials,
                           int* __restrict__ cursor, int N){
  int i = blockIdx.x*256 + threadIdx.x;
  if (i >= N) return;
  int ro = row_off[i] + partials[blockIdx.x];
  row_off[i] = ro;
  cursor[i]  = ro;
}

// fill padding slots with dummy node index N (Z/Z2 row N is zeroed)
__global__ void k_pad(const int* __restrict__ cnt, const int* __restrict__ row_off,
                      int* __restrict__ csr_src, int N){
  int i = blockIdx.x*256 + threadIdx.x;
  if (i >= N) return;
  int d  = cnt[i];
  int pd = (d + 7) & ~7;
  int ro = row_off[i];
  for (int p = d; p < pd; p++) csr_src[ro + p] = N;
}

// ---------------- fill ----------------
__global__ void k_fill(const int* __restrict__ src, const int* __restrict__ dst,
                       int* __restrict__ cursor, int* __restrict__ csr_src, int E){
  int e = blockIdx.x*256 + threadIdx.x;
  if (e >= E) return;
  int d = dst[e];
  int pos = atomicAdd(&cursor[d], 1);
  csr_src[pos] = src[e];
}

// ---------------- layer-1 dual GEMM: Z = X@Wl^T, S = X@Wr^T + (bl+br) ----------------
// fp32 A input, permuted-col bf16 output. Register-prefetch pipelined (R5).
__global__ __launch_bounds__(256, 2)
void k_dualgemm1(const float* __restrict__ X, const unsigned short* __restrict__ Wcat,
                 const float* __restrict__ bl, const float* __restrict__ br,
                 unsigned short* __restrict__ Z, unsigned short* __restrict__ S,
                 int N, int nrb){
  __shared__ unsigned short lds[64*FDIM];
  const int tid  = threadIdx.x;
  const int wave = tid >> 6;
  const int lane = tid & 63;
  const int n = lane & 15, q = lane >> 4;

  float bias[4];
#pragma unroll
  for (int ctl = 0; ctl < 4; ctl++){
    int ct = wave*4 + ctl;
    if (ct >= 8){ int col = (ct - 8)*16 + n; bias[ctl] = bl[col] + br[col]; }
    else bias[ctl] = 0.0f;
  }

  float4 pf[8];
  const int r_   = tid >> 4;
  const int c16_ = tid & 15;

  auto issue_load = [&](int rb){
    int row0 = rb*64;
#pragma unroll
    for (int it = 0; it < 4; it++){
      int r  = r_ + it*16;
      int gr = row0 + r;
      if (gr < N){
        const float4* sp = (const float4*)(X + (size_t)gr*FDIM + c16_*8);
        pf[2*it]   = sp[0];
        pf[2*it+1] = sp[1];
      } else {
        pf[2*it]   = make_float4(0,0,0,0);
        pf[2*it+1] = make_float4(0,0,0,0);
      }
    }
  };

  int rb = blockIdx.x;
  if (rb < nrb) issue_load(rb);

  for (; rb < nrb; rb += gridDim.x){
    int row0 = rb*64;
    __syncthreads();
#pragma unroll
    for (int it = 0; it < 4; it++){
      int r = r_ + it*16;
      float4 v0 = pf[2*it], v1 = pf[2*it+1];
      bf16x8 p;
      p[0] = (short)f2bf(v0.x); p[1] = (short)f2bf(v0.y);
      p[2] = (short)f2bf(v0.z); p[3] = (short)f2bf(v0.w);
      p[4] = (short)f2bf(v1.x); p[5] = (short)f2bf(v1.y);
      p[6] = (short)f2bf(v1.z); p[7] = (short)f2bf(v1.w);
      *(bf16x8*)(lds + r*FDIM + ((c16_ ^ (r & 15)) * 8)) = p;
    }
    __syncthreads();

    int rbn = rb + gridDim.x;
    if (rbn < nrb) issue_load(rbn);

    f32x4 acc[4][4];
#pragma unroll
    for (int rt = 0; rt < 4; rt++)
#pragma unroll
      for (int ctl = 0; ctl < 4; ctl++)
        acc[rt][ctl] = (f32x4){0.f, 0.f, 0.f, 0.f};

#pragma unroll
    for (int kk = 0; kk < 4; kk++){
      bf16x8 bfr[4];
#pragma unroll
      for (int ctl = 0; ctl < 4; ctl++){
        int row = (wave*4 + ctl)*16 + n;
        bfr[ctl] = *(const bf16x8*)(Wcat + row*FDIM + kk*32 + q*8);
      }
      bf16x8 afr[4];
#pragma unroll
      for (int rt = 0; rt < 4; rt++){
        int r = rt*16 + n;
        int c16 = (kk*4 + q) ^ n;
        afr[rt] = *(const bf16x8*)(lds + r*FDIM + c16*8);
      }
#pragma unroll
      for (int rt = 0; rt < 4; rt++)
#pragma unroll
        for (int ctl = 0; ctl < 4; ctl++)
          acc[rt][ctl] = __builtin_amdgcn_mfma_f32_16x16x32_bf16(
              afr[rt], bfr[ctl], acc[rt][ctl], 0, 0, 0);
    }

    unsigned short* dstb = (wave < 2) ? Z : S;
    int s0 = 64*(wave & 1) + n*4;
#pragma unroll
    for (int rt = 0; rt < 4; rt++){
#pragma unroll
      for (int r = 0; r < 4; r++){
        int grow = row0 + rt*16 + q*4 + r;
        if (grow < N){
          float v0 = acc[rt][0][r] + bias[0];
          float v1 = acc[rt][1][r] + bias[1];
          float v2 = acc[rt][2][r] + bias[2];
          float v3 = acc[rt][3][r] + bias[3];
          uint2 u;
          u.x = ((unsigned)f2bf(v1) << 16) | (unsigned)f2bf(v0);
          u.y = ((unsigned)f2bf(v3) << 16) | (unsigned)f2bf(v2);
          *(uint2*)(dstb + (size_t)grow*FDIM + s0) = u;
        }
      }
    }
  }
}

// ---------------- fused layer-1 aggregate + layer-2 dual GEMM ----------------
// Staging computes h = relu(mean(Z[src]) + S) on the fly (permuted space) into
// LDS, then MFMA with layer-2 weights. Z2 separate from Z (cross-block gather
// reads); S reused in place (row-disjoint across blocks, read-before-write).
__global__ __launch_bounds__(256, 2)
void k_agg_gemm(const unsigned short* __restrict__ Z, unsigned short* __restrict__ S,
                const int* __restrict__ row_off, const int* __restrict__ cnt,
                const int* __restrict__ csr_src,
                const unsigned short* __restrict__ Wcat,
                const float* __restrict__ bl, const float* __restrict__ br,
                unsigned short* __restrict__ Z2, int N, int nrb){
  __shared__ unsigned short lds[64*FDIM];
  const int tid  = threadIdx.x;
  const int wave = tid >> 6;
  const int lane = tid & 63;
  const int n = lane & 15, q = lane >> 4;
  const int g16   = lane & 15;   // pos within 16-lane row-group == 16B chunk idx
  const int gbase = lane & 48;   // first lane of this row-group

  float bias[4];
#pragma unroll
  for (int ctl = 0; ctl < 4; ctl++){
    int ct = wave*4 + ctl;
    if (ct >= 8){ int col = (ct - 8)*16 + n; bias[ctl] = bl[col] + br[col]; }
    else bias[ctl] = 0.0f;
  }

  for (int rb = blockIdx.x; rb < nrb; rb += gridDim.x){
    int row0 = rb*64;
    __syncthreads();
    // ---- staging: build h rows (layer-1 aggregate, permuted space) ----
#pragma unroll
    for (int it = 0; it < 4; it++){
      int r  = (tid >> 4) + it*16;
      int gr = row0 + r;
      bf16x8 p;
      if (gr < N){
        int ro  = row_off[gr];
        int deg = cnt[gr];
        float inv = 1.0f / (float)(deg > 1 ? deg : 1);
        float hacc[8];
#pragma unroll
        for (int z = 0; z < 8; z++) hacc[z] = 0.f;
        for (int base = 0; base < deg; base += 16){
          int m = deg - base; if (m > 16) m = 16;
          int sidx = (g16 < m) ? csr_src[ro + base + g16] : 0;
          for (int j = 0; j < m; j += 8){
            int id[8];
#pragma unroll
            for (int t = 0; t < 8; t++){
              int sl = j + t; if (sl >= m) sl = 0;      // group-uniform clamp
              id[t] = __shfl(sidx, gbase + sl);
            }
            uint4 v[8];
#pragma unroll
            for (int t = 0; t < 8; t++){
              unsigned u = (unsigned)id[t];
              if (u > (unsigned)N) u = (unsigned)N;     // defensive (row N = zeros)
              v[t] = *(const uint4*)(Z + (size_t)u*FDIM + g16*8);  // 8 gathers in flight
            }
#pragma unroll
            for (int t = 0; t < 8; t++){
              if (j + t < m){
                hacc[0] += __uint_as_float(v[t].x << 16);
                hacc[1] += __uint_as_float(v[t].x & 0xFFFF0000u);
                hacc[2] += __uint_as_float(v[t].y << 16);
                hacc[3] += __uint_as_float(v[t].y & 0xFFFF0000u);
                hacc[4] += __uint_as_float(v[t].z << 16);
                hacc[5] += __uint_as_float(v[t].z & 0xFFFF0000u);
                hacc[6] += __uint_as_float(v[t].w << 16);
                hacc[7] += __uint_as_float(v[t].w & 0xFFFF0000u);
              }
            }
          }
        }
        uint4 sv = *(const uint4*)(S + (size_t)gr*FDIM + g16*8);
        float s0 = __uint_as_float(sv.x << 16), s1 = __uint_as_float(sv.x & 0xFFFF0000u);
        float s2 = __uint_as_float(sv.y << 16), s3 = __uint_as_float(sv.y & 0xFFFF0000u);
        float s4 = __uint_as_float(sv.z << 16), s5 = __uint_as_float(sv.z & 0xFFFF0000u);
        float s6 = __uint_as_float(sv.w << 16), s7 = __uint_as_float(sv.w & 0xFFFF0000u);
        p[0] = (short)f2bf(fmaxf(hacc[0]*inv + s0, 0.f));
        p[1] = (short)f2bf(fmaxf(hacc[1]*inv + s1, 0.f));
        p[2] = (short)f2bf(fmaxf(hacc[2]*inv + s2, 0.f));
        p[3] = (short)f2bf(fmaxf(hacc[3]*inv + s3, 0.f));
        p[4] = (short)f2bf(fmaxf(hacc[4]*inv + s4, 0.f));
        p[5] = (short)f2bf(fmaxf(hacc[5]*inv + s5, 0.f));
        p[6] = (short)f2bf(fmaxf(hacc[6]*inv + s6, 0.f));
        p[7] = (short)f2bf(fmaxf(hacc[7]*inv + s7, 0.f));
      } else {
#pragma unroll
        for (int z = 0; z < 8; z++) p[z] = 0;
      }
      *(bf16x8*)(lds + r*FDIM + ((g16 ^ (r & 15)) * 8)) = p;
    }
    __syncthreads();

    // ---- MFMA with layer-2 weights ----
    f32x4 acc[4][4];
#pragma unroll
    for (int rt = 0; rt < 4; rt++)
#pragma unroll
      for (int ctl = 0; ctl < 4; ctl++)
        acc[rt][ctl] = (f32x4){0.f, 0.f, 0.f, 0.f};

#pragma unroll
    for (int kk = 0; kk < 4; kk++){
      bf16x8 bfr[4];
#pragma unroll
      for (int ctl = 0; ctl < 4; ctl++){
        int row = (wave*4 + ctl)*16 + n;
        bfr[ctl] = *(const bf16x8*)(Wcat + row*FDIM + kk*32 + q*8);
      }
      bf16x8 afr[4];
#pragma unroll
      for (int rt = 0; rt < 4; rt++){
        int r = rt*16 + n;
        int c16 = (kk*4 + q) ^ n;
        afr[rt] = *(const bf16x8*)(lds + r*FDIM + c16*8);
      }
#pragma unroll
      for (int rt = 0; rt < 4; rt++)
#pragma unroll
        for (int ctl = 0; ctl < 4; ctl++)
          acc[rt][ctl] = __builtin_amdgcn_mfma_f32_16x16x32_bf16(
              afr[rt], bfr[ctl], acc[rt][ctl], 0, 0, 0);
    }

    // ---- epilogue: Z2 / S (in place) ----
    unsigned short* dstb = (wave < 2) ? Z2 : S;
    int s0c = 64*(wave & 1) + n*4;
#pragma unroll
    for (int rt = 0; rt < 4; rt++){
#pragma unroll
      for (int r = 0; r < 4; r++){
        int grow = row0 + rt*16 + q*4 + r;
        if (grow < N){
          float v0 = acc[rt][0][r] + bias[0];
          float v1 = acc[rt][1][r] + bias[1];
          float v2 = acc[rt][2][r] + bias[2];
          float v3 = acc[rt][3][r] + bias[3];
          uint2 u;
          u.x = ((unsigned)f2bf(v1) << 16) | (unsigned)f2bf(v0);
          u.y = ((unsigned)f2bf(v3) << 16) | (unsigned)f2bf(v2);
          *(uint2*)(dstb + (size_t)grow*FDIM + s0c) = u;
        }
      }
    }
  }
}

// ---------------- final aggregate: out = relu(sum(Z2[src])/deg + S) ----------------
__global__ __launch_bounds__(256)
void k_aggregate(const unsigned short* __restrict__ Z2, const unsigned short* __restrict__ S,
                 const int* __restrict__ row_off, const int* __restrict__ cnt,
                 const int* __restrict__ csr_src, float* __restrict__ Out, int N){
  int wave = threadIdx.x >> 6, lane = threadIdx.x & 63;
  int node = blockIdx.x*4 + wave;
  if (node >= N) return;
  int start = row_off[node];
  int deg   = cnt[node];
  int pdeg  = (deg + 7) & ~7;
  float inv = 1.0f / (float)(deg > 1 ? deg : 1);
  int L = lane & 31, half = lane >> 5;
  uint2 sv = *(const uint2*)(S + (size_t)node*FDIM + L*4);

  const int* cb = csr_src + start;
  float a0 = 0.f, a1 = 0.f, a2 = 0.f, a3 = 0.f;
  for (int base = 0; base < pdeg; base += 64){
    int m = pdeg - base; if (m > 64) m = 64;      // multiple of 8
    int sidx = (lane < m) ? cb[base + lane] : N;
    for (int j = 0; j < m; j += 8){
      int id[4];
#pragma unroll
      for (int t = 0; t < 4; t++)
        id[t] = __shfl(sidx, j + 2*t + half);
      uint2 v[4];
#pragma unroll
      for (int t = 0; t < 4; t++){
        unsigned u = (unsigned)id[t];
        if (u > (unsigned)N) u = (unsigned)N;     // dummy/defensive -> zero row
        v[t] = *(const uint2*)(Z2 + (size_t)u*FDIM + L*4);
      }
#pragma unroll
      for (int t = 0; t < 4; t++){
        a0 += __uint_as_float(v[t].x << 16);
        a1 += __uint_as_float(v[t].x & 0xFFFF0000u);
        a2 += __uint_as_float(v[t].y << 16);
        a3 += __uint_as_float(v[t].y & 0xFFFF0000u);
      }
    }
  }
  a0 += __shfl_xor(a0, 32);
  a1 += __shfl_xor(a1, 32);
  a2 += __shfl_xor(a2, 32);
  a3 += __shfl_xor(a3, 32);
  float o0 = fmaxf(a0*inv + __uint_as_float(sv.x << 16),          0.f);
  float o1 = fmaxf(a1*inv + __uint_as_float(sv.x & 0xFFFF0000u),  0.f);
  float o2 = fmaxf(a2*inv + __uint_as_float(sv.y << 16),          0.f);
  float o3 = fmaxf(a3*inv + __uint_as_float(sv.y & 0xFFFF0000u),  0.f);
  // un-permute: stored s = L*4+e -> orig c = (e+4*hi)*16 + nn
  int nn = L & 15, hi = L >> 4;
  float e0v = half ? o2 : o0;
  float e1v = half ? o3 : o1;
  int e0 = 2*half, e1 = 2*half + 1;
  Out[(size_t)node*FDIM + (e0 + 4*hi)*16 + nn] = e0v;
  Out[(size_t)node*FDIM + (e1 + 4*hi)*16 + nn] = e1v;
}

extern "C" void kernel_launch(void* const* d_in, const int* in_sizes, int n_in,
                              void* d_out, int out_size, void* d_ws, size_t ws_size,
                              hipStream_t stream){
  const float* x   = (const float*)d_in[0];
  const int*   eix = (const int*)d_in[1];
  const float* Wl0 = (const float*)d_in[2];
  const float* bl0 = (const float*)d_in[3];
  const float* Wr0 = (const float*)d_in[4];
  const float* br0 = (const float*)d_in[5];
  const float* Wl1 = (const float*)d_in[6];
  const float* bl1 = (const float*)d_in[7];
  const float* Wr1 = (const float*)d_in[8];
  const float* br1 = (const float*)d_in[9];
  float* out = (float*)d_out;

  int N = in_sizes[0] / FDIM;
  int E = in_sizes[1] / 2;
  const int* src = eix;
  const int* dst = eix + E;

  // workspace (Z and Z2 have N+1 rows: row N is the zero dummy row)
  unsigned short* Z    = (unsigned short*)d_ws;
  unsigned short* Z2   = Z  + (size_t)(N + 1)*FDIM;
  unsigned short* S    = Z2 + (size_t)(N + 1)*FDIM;
  unsigned short* Wcat = S  + (size_t)N*FDIM;
  int* cnt     = (int*)(Wcat + 2*256*128);
  int* row_off = cnt + N;
  int* cursor  = row_off + N;
  int* csr_src = cursor + N;                 // capacity: E + 7N (padding bound)
  int* partials= csr_src + (E + 7*N);

  int nb = (N + 255)/256;

  k_init         <<<nb + 256, 256, 0, stream>>>(Wl0, Wr0, Wl1, Wr1, Wcat, cnt,
                                                Z + (size_t)N*FDIM, Z2 + (size_t)N*FDIM, N, nb);
  k_degree       <<<(E + 255)/256, 256, 0, stream>>>(dst, cnt, E);
  k_scan_blocks  <<<nb, 256, 0, stream>>>(cnt, row_off, partials, N);
  k_scan_partials<<<1, 512, 0, stream>>>(partials, nb);
  k_finalize     <<<nb, 256, 0, stream>>>(row_off, partials, cursor, N);
  k_fill         <<<(E + 255)/256, 256, 0, stream>>>(src, dst, cursor, csr_src, E);
  k_pad          <<<nb, 256, 0, stream>>>(cnt, row_off, csr_src, N);

  int nrb = (N + 63)/64;
  k_dualgemm1<<<512, 256, 0, stream>>>(x, Wcat, bl0, br0, Z, S, N, nrb);
  k_agg_gemm <<<512, 256, 0, stream>>>(Z, S, row_off, cnt, csr_src,
                                       Wcat + 256*128, bl1, br1, Z2, N, nrb);
  k_aggregate<<<(N + 3)/4, 256, 0, stream>>>(Z2, S, row_off, cnt, csr_src, out, N);
}